// Round 28
// baseline (5414.557 us; speedup 1.0000x reference)
//
#include <hip/hip_runtime.h>

// DIAGNOSTIC ROUND 28: the GRID HOLE — (asc-FMA dot, hsum sq, C1):
//   sq  = round(round(q0+q2)+q1)   (np.einsum('bnd,bnd->bn') same-operand
//                                   SOP, NPYV masked-load + hsum tree)
//   dot = fma(z,z', fma(y,y', round(x*x')))  (np.matmul / OpenBLAS asc-FMA)
//   dist = round( round(sq_n + sq_m) - 2*dot )   <-- C1, single-expression:
//          dists = sq[:,:,None] + sq[:,None,:] - 2.0*dot
// Rationale: hand-written np ref (transliterations all rejected); its C2
// sibling (r21) = global best 0.2666016; C1 flips the second-rounding bits
// at the ~2e-9 scale of the residual 1-2 queries. This cell was never run.
// Pipeline = r6-validated dumb version.

#define NPTS 4096
#define BATCH 8
#define TROWS (BATCH * NPTS)   // 32768

__device__ __forceinline__ float opaque(float x){ asm volatile("" : "+v"(x)); return x; }

// ---------------------------------------------------------------------------
// kNN. 64 queries/block, 4 threads/query, LDS merge.
// Tie-break smaller index (ties proven nonexistent, r17/r24).
// ---------------------------------------------------------------------------
__global__ __launch_bounds__(256) void knn_kernel(const float* __restrict__ xyz,
                                                  int* __restrict__ knn){
  __shared__ __align__(16) float4 pts[NPTS];   // 64KB
  __shared__ float cd[64*69];
  __shared__ int   ci[64*69];

  int t = threadIdx.x;
  int b  = blockIdx.x >> 6;
  int qb = (blockIdx.x & 63) * 64;
  const float* xb = xyz + b*NPTS*3;

  for (int i = t; i < NPTS; i += 256){
    float x = xb[3*i], y = xb[3*i+1], z = xb[3*i+2];
    float q0 = opaque(x*x), q1 = opaque(y*y), q2 = opaque(z*z);
    float s02 = opaque(q0 + q2);           // einsum same-operand: hsum tree
    float s   = opaque(s02 + q1);
    pts[i] = make_float4(x, y, z, s);
  }
  __syncthreads();

  int q = qb + (t >> 2), part = t & 3;
  float4 Pq = pts[q];

  float bd[16]; int bi[16];
  #pragma unroll
  for (int s = 0; s < 16; s++){ bd[s] = 1e30f; bi[s] = 0x7fffffff; }
  float worst = 1e30f; int wIdx = 0x7fffffff; int wslot = 0;

  for (int m = part; m < NPTS; m += 4){
    float4 P = pts[m];
    float p0 = opaque(Pq.x*P.x);              // round(x*x')
    float f1 = opaque(fmaf(Pq.y, P.y, p0));   // fma(y,y', .)
    float d  = opaque(fmaf(Pq.z, P.z, f1));   // fma(z,z', .)  BLAS asc-FMA
    float ssum = opaque(Pq.w + P.w);          // (sq_n + sq_m), one rounding
    float dist = opaque(ssum - 2.0f*d);       // - 2*dot (exact), one rounding
    if (dist < worst || (dist == worst && m < wIdx)){
      #pragma unroll
      for (int s = 0; s < 16; s++) if (s == wslot){ bd[s] = dist; bi[s] = m; }
      float w2 = bd[0]; int i2 = bi[0]; int s2 = 0;
      #pragma unroll
      for (int s = 1; s < 16; s++){
        bool gt = (bd[s] > w2) || (bd[s] == w2 && bi[s] > i2);
        if (gt){ w2 = bd[s]; i2 = bi[s]; s2 = s; }
      }
      worst = w2; wIdx = i2; wslot = s2;
    }
  }

  int q64 = t >> 2;
  #pragma unroll
  for (int s = 0; s < 16; s++){
    cd[q64*69 + part*16 + s] = bd[s];
    ci[q64*69 + part*16 + s] = bi[s];
  }
  __syncthreads();

  if (t < 64){
    int row = b*NPTS + qb + t;
    float* cdq = cd + t*69; int* ciq = ci + t*69;
    for (int pass = 0; pass < 16; pass++){
      float best = cdq[0]; int bidx = ciq[0]; int bs = 0;
      for (int i = 1; i < 64; i++){
        float v = cdq[i]; int ix = ciq[i];
        if (v < best || (v == best && ix < bidx)){ best = v; bidx = ix; bs = i; }
      }
      knn[row*16 + pass] = bidx;
      cdq[bs] = 1e30f;
    }
  }
}

// ---------------------------------------------------------------------------
// Dumb GEMM (validated r6).
// ---------------------------------------------------------------------------
template<int KD>
__global__ __launch_bounds__(256) void gemm_simple(const float* __restrict__ A,
                                                   const float* __restrict__ W,
                                                   const float* __restrict__ bias,
                                                   float* __restrict__ out){
  long total = (long)TROWS * 128;
  for (long id = (long)blockIdx.x*256 + threadIdx.x; id < total;
       id += (long)gridDim.x*256){
    int r = (int)(id >> 7), c = (int)(id & 127);
    float acc = bias ? bias[c] : 0.f;
    const float* a = A + (long)r*KD;
    for (int k = 0; k < KD; k++) acc = fmaf(a[k], W[k*128+c], acc);
    out[id] = acc;
  }
}

// ---------------------------------------------------------------------------
// Dumb fused core (validated r6).
// ---------------------------------------------------------------------------
__global__ __launch_bounds__(128) void pt_core_simple(
    const float* __restrict__ xyz, const int* __restrict__ knn,
    const float* __restrict__ Qf, const float* __restrict__ Kf, const float* __restrict__ Vf,
    const float* __restrict__ d1w, const float* __restrict__ d1b,
    const float* __restrict__ d2w, const float* __restrict__ d2b,
    const float* __restrict__ g1w, const float* __restrict__ g1b,
    const float* __restrict__ g2w, const float* __restrict__ g2b,
    float* __restrict__ agg_out){
  __shared__ float T[16][128];
  __shared__ float P[16][128];
  __shared__ float H[16][128];
  __shared__ float A1[16][128];
  __shared__ int   idx[16];
  __shared__ float rel[16][3];

  int n = blockIdx.x;
  int c = threadIdx.x;
  int b = n >> 12;

  if (c < 16){
    int gi = b*NPTS + knn[n*16 + c];
    idx[c] = gi;
    rel[c][0] = xyz[n*3+0] - xyz[gi*3+0];
    rel[c][1] = xyz[n*3+1] - xyz[gi*3+1];
    rel[c][2] = xyz[n*3+2] - xyz[gi*3+2];
  }
  __syncthreads();

  for (int j = 0; j < 16; j++){
    float v = d1b[c];
    v = fmaf(rel[j][0], d1w[0*128 + c], v);
    v = fmaf(rel[j][1], d1w[1*128 + c], v);
    v = fmaf(rel[j][2], d1w[2*128 + c], v);
    T[j][c] = fmaxf(v, 0.f);
  }
  __syncthreads();

  for (int j = 0; j < 16; j++){
    float acc = d2b[c];
    for (int k = 0; k < 128; k++) acc = fmaf(T[j][k], d2w[k*128 + c], acc);
    P[j][c] = acc;
  }
  __syncthreads();

  float q = Qf[(long)n*128 + c];
  for (int j = 0; j < 16; j++)
    H[j][c] = q - Kf[(long)idx[j]*128 + c] + P[j][c];
  __syncthreads();

  for (int j = 0; j < 16; j++){
    float acc = g1b[c];
    for (int k = 0; k < 128; k++) acc = fmaf(H[j][k], g1w[k*128 + c], acc);
    A1[j][c] = fmaxf(acc, 0.f);
  }
  __syncthreads();

  float l[16];
  #pragma unroll
  for (int j = 0; j < 16; j++){
    float acc = g2b[c];
    for (int k = 0; k < 128; k++) acc = fmaf(A1[j][k], g2w[k*128 + c], acc);
    l[j] = acc * 0.08838834764831845f;
  }
  float m = l[0];
  #pragma unroll
  for (int j = 1; j < 16; j++) m = fmaxf(m, l[j]);
  float s = 0.f;
  #pragma unroll
  for (int j = 0; j < 16; j++){ l[j] = __expf(l[j] - m); s += l[j]; }
  float inv = 1.f / s;
  float agg = 0.f;
  #pragma unroll
  for (int j = 0; j < 16; j++)
    agg = fmaf(l[j]*inv, Vf[(long)idx[j]*128 + c] + P[j][c], agg);
  agg_out[(long)n*128 + c] = agg;
}

// ---------------------------------------------------------------------------
extern "C" void kernel_launch(void* const* d_in, const int* in_sizes, int n_in,
                              void* d_out, int out_size, void* d_ws, size_t ws_size,
                              hipStream_t stream) {
  const float* xyz      = (const float*)d_in[0];
  const float* features = (const float*)d_in[1];
  const float* fc1_w    = (const float*)d_in[2];
  const float* fc1_b    = (const float*)d_in[3];
  const float* fc2_w    = (const float*)d_in[4];
  const float* fc2_b    = (const float*)d_in[5];
  const float* d1_w     = (const float*)d_in[6];
  const float* d1_b     = (const float*)d_in[7];
  const float* d2_w     = (const float*)d_in[8];
  const float* d2_b     = (const float*)d_in[9];
  const float* g1_w     = (const float*)d_in[10];
  const float* g1_b     = (const float*)d_in[11];
  const float* g2_w     = (const float*)d_in[12];
  const float* g2_b     = (const float*)d_in[13];
  const float* wq_w     = (const float*)d_in[14];
  const float* wk_w     = (const float*)d_in[15];
  const float* wv_w     = (const float*)d_in[16];
  float* out = (float*)d_out;

  char* ws = (char*)d_ws;
  const size_t SZ = (size_t)TROWS * 128 * sizeof(float);
  float* X  = (float*)(ws);
  float* AG = (float*)(ws);
  float* Qf = (float*)(ws + SZ);
  float* Kf = (float*)(ws + 2*SZ);
  float* Vf = (float*)(ws + 3*SZ);
  int*   kn = (int*)  (ws + 4*SZ);

  knn_kernel<<<dim3(512), dim3(256), 0, stream>>>(xyz, kn);
  gemm_simple<64> <<<dim3(8192), dim3(256), 0, stream>>>(features, fc1_w, fc1_b, X);
  gemm_simple<128><<<dim3(8192), dim3(256), 0, stream>>>(X, wq_w, nullptr, Qf);
  gemm_simple<128><<<dim3(8192), dim3(256), 0, stream>>>(X, wk_w, nullptr, Kf);
  gemm_simple<128><<<dim3(8192), dim3(256), 0, stream>>>(X, wv_w, nullptr, Vf);
  pt_core_simple<<<dim3(TROWS), dim3(128), 0, stream>>>(xyz, kn, Qf, Kf, Vf,
                                                        d1_w, d1_b, d2_w, d2_b,
                                                        g1_w, g1_b, g2_w, g2_b, AG);
  gemm_simple<128><<<dim3(8192), dim3(256), 0, stream>>>(AG, fc2_w, fc2_b, out);
}

// Round 29
// 2995.863 us; speedup vs baseline: 1.8073x; 1.8073x over previous
//
#include <hip/hip_runtime.h>

// PointTransformerLayer — WORKING scheme (r28): kNN = asc-FMA dot (BLAS
// matmul), hsum sq (NPYV einsum norms), C1 combine. FROZEN — do not touch.
// This round: reinstate the fast pipeline (r1-validated, bitwise-equivalent
// to the dumb r6 pipeline) around the winning knn.
//   X = features@fc1+b            (gemm_k<64>)
//   Q,K,V = X@wq/wk/wv            (gemm_k<128> x3)
//   agg = fused pos_enc/attn/softmax/aggregate (pt_core) -> d_out
//   out = agg@fc2+b               (gemm_k<128>, in-place on d_out)

#define NPTS 4096
#define BATCH 8
#define TROWS (BATCH * NPTS)   // 32768

__device__ __forceinline__ float4 ld4(const float* p){ return *reinterpret_cast<const float4*>(p); }
__device__ __forceinline__ void st4(float* p, float4 v){ *reinterpret_cast<float4*>(p) = v; }
__device__ __forceinline__ float opaque(float x){ asm volatile("" : "+v"(x)); return x; }

// ---------------------------------------------------------------------------
// kNN — WINNING BITS (r28). asc-FMA dot, hsum sq, C1. Tie-break smaller idx.
// ---------------------------------------------------------------------------
__global__ __launch_bounds__(256) void knn_kernel(const float* __restrict__ xyz,
                                                  int* __restrict__ knn){
  __shared__ __align__(16) float4 pts[NPTS];   // 64KB
  __shared__ float cd[64*69];
  __shared__ int   ci[64*69];

  int t = threadIdx.x;
  int b  = blockIdx.x >> 6;
  int qb = (blockIdx.x & 63) * 64;
  const float* xb = xyz + b*NPTS*3;

  for (int i = t; i < NPTS; i += 256){
    float x = xb[3*i], y = xb[3*i+1], z = xb[3*i+2];
    float q0 = opaque(x*x), q1 = opaque(y*y), q2 = opaque(z*z);
    float s02 = opaque(q0 + q2);           // einsum same-operand: hsum tree
    float s   = opaque(s02 + q1);
    pts[i] = make_float4(x, y, z, s);
  }
  __syncthreads();

  int q = qb + (t >> 2), part = t & 3;
  float4 Pq = pts[q];

  float bd[16]; int bi[16];
  #pragma unroll
  for (int s = 0; s < 16; s++){ bd[s] = 1e30f; bi[s] = 0x7fffffff; }
  float worst = 1e30f; int wIdx = 0x7fffffff; int wslot = 0;

  for (int m = part; m < NPTS; m += 4){
    float4 P = pts[m];
    float p0 = opaque(Pq.x*P.x);              // round(x*x')
    float f1 = opaque(fmaf(Pq.y, P.y, p0));   // fma(y,y', .)
    float d  = opaque(fmaf(Pq.z, P.z, f1));   // fma(z,z', .)  BLAS asc-FMA
    float ssum = opaque(Pq.w + P.w);          // (sq_n + sq_m)
    float dist = opaque(ssum - 2.0f*d);       // C1
    if (dist < worst || (dist == worst && m < wIdx)){
      #pragma unroll
      for (int s = 0; s < 16; s++) if (s == wslot){ bd[s] = dist; bi[s] = m; }
      float w2 = bd[0]; int i2 = bi[0]; int s2 = 0;
      #pragma unroll
      for (int s = 1; s < 16; s++){
        bool gt = (bd[s] > w2) || (bd[s] == w2 && bi[s] > i2);
        if (gt){ w2 = bd[s]; i2 = bi[s]; s2 = s; }
      }
      worst = w2; wIdx = i2; wslot = s2;
    }
  }

  int q64 = t >> 2;
  #pragma unroll
  for (int s = 0; s < 16; s++){
    cd[q64*69 + part*16 + s] = bd[s];
    ci[q64*69 + part*16 + s] = bi[s];
  }
  __syncthreads();

  if (t < 64){
    int row = b*NPTS + qb + t;
    float* cdq = cd + t*69; int* ciq = ci + t*69;
    for (int pass = 0; pass < 16; pass++){
      float best = cdq[0]; int bidx = ciq[0]; int bs = 0;
      for (int i = 1; i < 64; i++){
        float v = cdq[i]; int ix = ciq[i];
        if (v < best || (v == best && ix < bidx)){ best = v; bidx = ix; bs = i; }
      }
      knn[row*16 + pass] = bidx;
      cdq[bs] = 1e30f;
    }
  }
}

// ---------------------------------------------------------------------------
// Tiled GEMM: rows x KD @ KD x 128 (+ optional bias). 64 rows/block, 256 thr.
// Thread owns 8 rows x 4 channels. In-place-safe (reads own rows to LDS
// before writing).
// ---------------------------------------------------------------------------
template<int KD>
__global__ __launch_bounds__(256) void gemm_k(const float* __restrict__ A,
                                              const float* __restrict__ Wg,
                                              const float* __restrict__ bias,
                                              float* __restrict__ out){
  __shared__ __align__(16) float Wl[KD*128];
  __shared__ __align__(16) float At[KD*68];

  int t = threadIdx.x;
  int r0 = blockIdx.x * 64;

  for (int i = t; i < KD*32; i += 256)
    reinterpret_cast<float4*>(Wl)[i] = reinterpret_cast<const float4*>(Wg)[i];
  {
    int kk = t & (KD-1); int rr = t / KD;
    for (int r = rr; r < 64; r += 256/KD)
      At[kk*68 + r] = A[(r0+r)*KD + kk];
  }
  __syncthreads();

  int lc = t & 31, ch = lc*4, rg = t >> 5;
  float bb[4] = {0.f, 0.f, 0.f, 0.f};
  if (bias){ float4 b4 = ld4(bias + ch); bb[0]=b4.x; bb[1]=b4.y; bb[2]=b4.z; bb[3]=b4.w; }
  float acc[8][4];
  #pragma unroll
  for (int j = 0; j < 8; j++){ acc[j][0]=bb[0]; acc[j][1]=bb[1]; acc[j][2]=bb[2]; acc[j][3]=bb[3]; }

  #pragma unroll 4
  for (int kk = 0; kk < KD; kk++){
    float4 w = ld4(&Wl[kk*128 + ch]);
    float4 a = ld4(&At[kk*68 + rg*8]);
    float4 b = ld4(&At[kk*68 + rg*8 + 4]);
    float wa[4] = {w.x, w.y, w.z, w.w};
    float ta[8] = {a.x, a.y, a.z, a.w, b.x, b.y, b.z, b.w};
    #pragma unroll
    for (int j = 0; j < 8; j++)
      #pragma unroll
      for (int c = 0; c < 4; c++)
        acc[j][c] = fmaf(ta[j], wa[c], acc[j][c]);
  }

  #pragma unroll
  for (int j = 0; j < 8; j++){
    int row = r0 + rg*8 + j;
    st4(&out[row*128 + ch], make_float4(acc[j][0], acc[j][1], acc[j][2], acc[j][3]));
  }
}

// ---------------------------------------------------------------------------
// Fused per-point core: 4 points/block (1/wave), 256 thr. Weights d2/g1/g2
// staged through one 64KB LDS buffer. Per-point tiles ch-major [128][16].
// Lane map: lc=lane&31 -> channels 4lc..4lc+3; half=lane>>5 -> 8 neighbors.
// ---------------------------------------------------------------------------
__device__ __forceinline__ void mm_step(const float* Wl, const float* bufp,
                                        int jo, int ch, float acc[8][4]){
  #pragma unroll 4
  for (int kk = 0; kk < 128; kk++){
    float4 w = ld4(&Wl[kk*128 + ch]);
    float4 a = ld4(&bufp[kk*16 + jo]);
    float4 b = ld4(&bufp[kk*16 + jo + 4]);
    float wa[4] = {w.x, w.y, w.z, w.w};
    float ta[8] = {a.x, a.y, a.z, a.w, b.x, b.y, b.z, b.w};
    #pragma unroll
    for (int j = 0; j < 8; j++)
      #pragma unroll
      for (int c = 0; c < 4; c++)
        acc[j][c] = fmaf(ta[j], wa[c], acc[j][c]);
  }
}

__global__ __launch_bounds__(256) void pt_core(
    const float* __restrict__ xyz, const int* __restrict__ knn,
    const float* __restrict__ Qf, const float* __restrict__ Kf, const float* __restrict__ Vf,
    const float* __restrict__ d1w, const float* __restrict__ d1b,
    const float* __restrict__ d2w, const float* __restrict__ d2b,
    const float* __restrict__ g1w, const float* __restrict__ g1b,
    const float* __restrict__ g2w, const float* __restrict__ g2b,
    float* __restrict__ agg_out){
  __shared__ __align__(16) float Wl[128*128];     // 64KB weight buffer
  __shared__ __align__(16) float buf[4][128*16];  // work tile (T/h/a1)
  __shared__ __align__(16) float pbuf[4][128*16]; // pos_enc
  __shared__ __align__(16) float rels[4][16*4];
  __shared__ int idxl[4][16];

  int tid = threadIdx.x;
  int wv = tid >> 6, lane = tid & 63, half = lane >> 5, lc = lane & 31;
  int ch = lc*4, jo = half*8;
  int n = blockIdx.x*4 + wv;

  for (int i = tid; i < 4096; i += 256)
    reinterpret_cast<float4*>(Wl)[i] = reinterpret_cast<const float4*>(d2w)[i];
  if (tid < 64){
    int p = tid >> 4, j = tid & 15;
    int row = blockIdx.x*4 + p;
    int gi = (row >> 12)*NPTS + knn[row*16 + j];
    idxl[p][j] = gi;
    rels[p][j*4+0] = xyz[row*3+0] - xyz[gi*3+0];
    rels[p][j*4+1] = xyz[row*3+1] - xyz[gi*3+1];
    rels[p][j*4+2] = xyz[row*3+2] - xyz[gi*3+2];
    rels[p][j*4+3] = 0.f;
  }
  float4 v0 = ld4(d1w + ch), v1 = ld4(d1w + 128 + ch), v2 = ld4(d1w + 256 + ch);
  float4 vb = ld4(d1b + ch);
  float dc[3][4] = {{v0.x,v0.y,v0.z,v0.w},{v1.x,v1.y,v1.z,v1.w},{v2.x,v2.y,v2.z,v2.w}};
  float db1[4] = {vb.x, vb.y, vb.z, vb.w};
  float4 b2 = ld4(d2b + ch); float db2[4] = {b2.x, b2.y, b2.z, b2.w};
  __syncthreads();

  float* bufp  = buf[wv];
  float* pbufp = pbuf[wv];

  // T = relu(rel @ d1 + d1_b)
  {
    float tv[4][8];
    #pragma unroll
    for (int jj = 0; jj < 8; jj++){
      float4 r = ld4(&rels[wv][(jo+jj)*4]);
      float rr[3] = {r.x, r.y, r.z};
      #pragma unroll
      for (int c = 0; c < 4; c++){
        float v = db1[c];
        #pragma unroll
        for (int cc = 0; cc < 3; cc++) v = fmaf(rr[cc], dc[cc][c], v);
        tv[c][jj] = fmaxf(v, 0.f);
      }
    }
    #pragma unroll
    for (int c = 0; c < 4; c++){
      st4(&bufp[(ch+c)*16 + jo],     make_float4(tv[c][0], tv[c][1], tv[c][2], tv[c][3]));
      st4(&bufp[(ch+c)*16 + jo + 4], make_float4(tv[c][4], tv[c][5], tv[c][6], tv[c][7]));
    }
  }
  __syncthreads();

  // pos_enc P = T @ d2 + d2_b
  float acc[8][4];
  #pragma unroll
  for (int j = 0; j < 8; j++){ acc[j][0]=db2[0]; acc[j][1]=db2[1]; acc[j][2]=db2[2]; acc[j][3]=db2[3]; }
  mm_step(Wl, bufp, jo, ch, acc);

  #pragma unroll
  for (int c = 0; c < 4; c++){
    st4(&pbufp[(ch+c)*16 + jo],     make_float4(acc[0][c], acc[1][c], acc[2][c], acc[3][c]));
    st4(&pbufp[(ch+c)*16 + jo + 4], make_float4(acc[4][c], acc[5][c], acc[6][c], acc[7][c]));
  }

  // h = q - k + P
  {
    float4 q4 = ld4(&Qf[(long)n*128 + ch]);
    float qa[4] = {q4.x, q4.y, q4.z, q4.w};
    float hv[8][4];
    #pragma unroll
    for (int jj = 0; jj < 8; jj++){
      int gi = idxl[wv][jo+jj];
      float4 k4 = ld4(&Kf[(long)gi*128 + ch]);
      float ka[4] = {k4.x, k4.y, k4.z, k4.w};
      #pragma unroll
      for (int c = 0; c < 4; c++) hv[jj][c] = qa[c] - ka[c] + acc[jj][c];
    }
    #pragma unroll
    for (int c = 0; c < 4; c++){
      st4(&bufp[(ch+c)*16 + jo],     make_float4(hv[0][c], hv[1][c], hv[2][c], hv[3][c]));
      st4(&bufp[(ch+c)*16 + jo + 4], make_float4(hv[4][c], hv[5][c], hv[6][c], hv[7][c]));
    }
  }
  __syncthreads();

  // W <- g1 ; a1 = relu(h @ g1 + g1_b)
  for (int i = tid; i < 4096; i += 256)
    reinterpret_cast<float4*>(Wl)[i] = reinterpret_cast<const float4*>(g1w)[i];
  __syncthreads();
  {
    float4 gb = ld4(g1b + ch); float g[4] = {gb.x, gb.y, gb.z, gb.w};
    #pragma unroll
    for (int j = 0; j < 8; j++){ acc[j][0]=g[0]; acc[j][1]=g[1]; acc[j][2]=g[2]; acc[j][3]=g[3]; }
  }
  mm_step(Wl, bufp, jo, ch, acc);
  #pragma unroll
  for (int j = 0; j < 8; j++)
    #pragma unroll
    for (int c = 0; c < 4; c++) acc[j][c] = fmaxf(acc[j][c], 0.f);
  __syncthreads();
  #pragma unroll
  for (int c = 0; c < 4; c++){
    st4(&bufp[(ch+c)*16 + jo],     make_float4(acc[0][c], acc[1][c], acc[2][c], acc[3][c]));
    st4(&bufp[(ch+c)*16 + jo + 4], make_float4(acc[4][c], acc[5][c], acc[6][c], acc[7][c]));
  }
  __syncthreads();

  // W <- g2 ; logits = a1 @ g2 + g2_b
  for (int i = tid; i < 4096; i += 256)
    reinterpret_cast<float4*>(Wl)[i] = reinterpret_cast<const float4*>(g2w)[i];
  __syncthreads();
  {
    float4 gb = ld4(g2b + ch); float g[4] = {gb.x, gb.y, gb.z, gb.w};
    #pragma unroll
    for (int j = 0; j < 8; j++){ acc[j][0]=g[0]; acc[j][1]=g[1]; acc[j][2]=g[2]; acc[j][3]=g[3]; }
  }
  mm_step(Wl, bufp, jo, ch, acc);

  // softmax over 16 neighbors per channel (halves via shfl_xor 32)
  const float sc = 0.08838834764831845f;  // 1/sqrt(128)
  #pragma unroll
  for (int j = 0; j < 8; j++)
    #pragma unroll
    for (int c = 0; c < 4; c++) acc[j][c] *= sc;
  float mx[4], inv[4];
  #pragma unroll
  for (int c = 0; c < 4; c++){
    float m = acc[0][c];
    #pragma unroll
    for (int j = 1; j < 8; j++) m = fmaxf(m, acc[j][c]);
    m = fmaxf(m, __shfl_xor(m, 32));
    mx[c] = m;
  }
  #pragma unroll
  for (int j = 0; j < 8; j++)
    #pragma unroll
    for (int c = 0; c < 4; c++) acc[j][c] = __expf(acc[j][c] - mx[c]);
  #pragma unroll
  for (int c = 0; c < 4; c++){
    float s = 0.f;
    #pragma unroll
    for (int j = 0; j < 8; j++) s += acc[j][c];
    s += __shfl_xor(s, 32);
    inv[c] = 1.0f / s;
  }
  #pragma unroll
  for (int j = 0; j < 8; j++)
    #pragma unroll
    for (int c = 0; c < 4; c++) acc[j][c] *= inv[c];

  // agg = sum_j attn * (V + P)
  float pv[4][8];
  #pragma unroll
  for (int c = 0; c < 4; c++){
    float4 pa = ld4(&pbufp[(ch+c)*16 + jo]);
    float4 pb = ld4(&pbufp[(ch+c)*16 + jo + 4]);
    pv[c][0]=pa.x; pv[c][1]=pa.y; pv[c][2]=pa.z; pv[c][3]=pa.w;
    pv[c][4]=pb.x; pv[c][5]=pb.y; pv[c][6]=pb.z; pv[c][7]=pb.w;
  }
  float ag[4] = {0.f, 0.f, 0.f, 0.f};
  #pragma unroll
  for (int jj = 0; jj < 8; jj++){
    int gi = idxl[wv][jo+jj];
    float4 v4 = ld4(&Vf[(long)gi*128 + ch]);
    float va[4] = {v4.x, v4.y, v4.z, v4.w};
    #pragma unroll
    for (int c = 0; c < 4; c++) ag[c] = fmaf(acc[jj][c], va[c] + pv[c][jj], ag[c]);
  }
  #pragma unroll
  for (int c = 0; c < 4; c++) ag[c] += __shfl_xor(ag[c], 32);
  if (half == 0)
    st4(&agg_out[(long)n*128 + ch], make_float4(ag[0], ag[1], ag[2], ag[3]));
}

// ---------------------------------------------------------------------------
extern "C" void kernel_launch(void* const* d_in, const int* in_sizes, int n_in,
                              void* d_out, int out_size, void* d_ws, size_t ws_size,
                              hipStream_t stream) {
  const float* xyz      = (const float*)d_in[0];
  const float* features = (const float*)d_in[1];
  const float* fc1_w    = (const float*)d_in[2];
  const float* fc1_b    = (const float*)d_in[3];
  const float* fc2_w    = (const float*)d_in[4];
  const float* fc2_b    = (const float*)d_in[5];
  const float* d1_w     = (const float*)d_in[6];
  const float* d1_b     = (const float*)d_in[7];
  const float* d2_w     = (const float*)d_in[8];
  const float* d2_b     = (const float*)d_in[9];
  const float* g1_w     = (const float*)d_in[10];
  const float* g1_b     = (const float*)d_in[11];
  const float* g2_w     = (const float*)d_in[12];
  const float* g2_b     = (const float*)d_in[13];
  const float* wq_w     = (const float*)d_in[14];
  const float* wk_w     = (const float*)d_in[15];
  const float* wv_w     = (const float*)d_in[16];
  float* out = (float*)d_out;

  char* ws = (char*)d_ws;
  const size_t SZ = (size_t)TROWS * 128 * sizeof(float);
  float* X  = (float*)(ws);
  float* Qf = (float*)(ws + SZ);
  float* Kf = (float*)(ws + 2*SZ);
  float* Vf = (float*)(ws + 3*SZ);
  int*   kn = (int*)  (ws + 4*SZ);

  knn_kernel<<<dim3(512), dim3(256), 0, stream>>>(xyz, kn);
  gemm_k<64> <<<dim3(TROWS/64), dim3(256), 0, stream>>>(features, fc1_w, fc1_b, X);
  gemm_k<128><<<dim3(TROWS/64), dim3(256), 0, stream>>>(X, wq_w, nullptr, Qf);
  gemm_k<128><<<dim3(TROWS/64), dim3(256), 0, stream>>>(X, wk_w, nullptr, Kf);
  gemm_k<128><<<dim3(TROWS/64), dim3(256), 0, stream>>>(X, wv_w, nullptr, Vf);
  pt_core<<<dim3(TROWS/4), dim3(256), 0, stream>>>(xyz, kn, Qf, Kf, Vf,
                                                   d1_w, d1_b, d2_w, d2_b,
                                                   g1_w, g1_b, g2_w, g2_b, out);
  gemm_k<128><<<dim3(TROWS/64), dim3(256), 0, stream>>>(out, fc2_w, fc2_b, out);
}

// Round 30
// 1425.471 us; speedup vs baseline: 3.7984x; 2.1017x over previous
//
#include <hip/hip_runtime.h>

// PointTransformerLayer. kNN bits FROZEN (r28): asc-FMA dot, hsum sq, C1.
// r30: threshold-collect kNN (old exact-scan kernel was 1742us: wave-any
// insert body every iteration at 4 waves/CU). Everything else = r29.

#define NPTS 4096
#define BATCH 8
#define TROWS (BATCH * NPTS)   // 32768
#define CAP 512
#define NQ 8                   // queries per knn block
#define NPART 32               // threads per query

__device__ __forceinline__ float4 ld4(const float* p){ return *reinterpret_cast<const float4*>(p); }
__device__ __forceinline__ void st4(float* p, float4 v){ *reinterpret_cast<float4*>(p) = v; }
__device__ __forceinline__ float opaque(float x){ asm volatile("" : "+v"(x)); return x; }

// ---------------------------------------------------------------------------
// pts4 = (x,y,z, sq) with WINNING sq bits (hsum: (q0+q2)+q1).
// ---------------------------------------------------------------------------
__global__ __launch_bounds__(256) void knn_prep(const float* __restrict__ xyz,
                                                float4* __restrict__ pts4){
  int i = blockIdx.x*256 + threadIdx.x;
  if (i >= TROWS) return;
  float x = xyz[3*i], y = xyz[3*i+1], z = xyz[3*i+2];
  float q0 = opaque(x*x), q1 = opaque(y*y), q2 = opaque(z*z);
  float s02 = opaque(q0 + q2);
  float s   = opaque(s02 + q1);
  pts4[i] = make_float4(x, y, z, s);
}

// ---------------------------------------------------------------------------
// Threshold-collect kNN. 8 queries/block, 32 threads/query.
// dist bits = r28 winner: fma-chain dot, C1 combine (opaque-fenced).
// Escalate T (x1.5) per query while count < 16; count>=16 => top-16 in buf.
// Selection: 16 passes of (dist,idx)-lex min over buffer => ascending order,
// identical to np argsort output. Append order nondeterministic but set +
// selection deterministic.
// ---------------------------------------------------------------------------
__global__ __launch_bounds__(256) void knn_collect(const float4* __restrict__ pts4,
                                                   int* __restrict__ knn){
  __shared__ float bufd[NQ][CAP];   // 16KB
  __shared__ int   bufi[NQ][CAP];   // 16KB
  __shared__ int   cnt[NQ];
  __shared__ int   anyflag;

  int tid = threadIdx.x;
  int qi = tid >> 5, part = tid & 31;
  int b  = blockIdx.x / (NPTS/NQ);
  int q0 = (blockIdx.x % (NPTS/NQ)) * NQ;
  int row = b*NPTS + q0 + qi;
  const float4* base = pts4 + b*NPTS;
  float4 Pq = pts4[row];

  float T = 0.03f;
  for (int round = 0; round < 14; ++round){
    if (tid == 0) anyflag = 0;
    __syncthreads();
    bool active = (round == 0) || (cnt[qi] < 16);
    __syncthreads();
    if (active && part == 0){ cnt[qi] = 0; anyflag = 1; }
    __syncthreads();
    if (!anyflag) break;
    if (active){
      for (int i = part; i < NPTS; i += NPART){
        float4 P = base[i];
        float p0 = opaque(Pq.x*P.x);              // round(x*x')
        float f1 = opaque(fmaf(Pq.y, P.y, p0));   // fma(y,y', .)
        float d  = opaque(fmaf(Pq.z, P.z, f1));   // fma(z,z', .)
        float ssum = opaque(Pq.w + P.w);          // sq_n + sq_m
        float dist = opaque(ssum - 2.0f*d);       // C1
        if (dist < T){
          int p = atomicAdd(&cnt[qi], 1);
          if (p < CAP){ bufd[qi][p] = dist; bufi[qi][p] = i; }
        }
      }
    }
    T *= 1.5f;
    __syncthreads();
  }

  int n_c = cnt[qi]; if (n_c > CAP) n_c = CAP;
  for (int pass = 0; pass < 16; ++pass){
    float bd = 1e30f; int bi_ = 0x7fffffff; int bs = 0;
    for (int e = part; e < n_c; e += NPART){
      float v = bufd[qi][e]; int ix = bufi[qi][e];
      if (v < bd || (v == bd && ix < bi_)){ bd = v; bi_ = ix; bs = e; }
    }
    #pragma unroll
    for (int off = 1; off < 32; off <<= 1){
      float od = __shfl_xor(bd, off); int oi = __shfl_xor(bi_, off); int os = __shfl_xor(bs, off);
      if (od < bd || (od == bd && oi < bi_)){ bd = od; bi_ = oi; bs = os; }
    }
    if (part == 0){ knn[row*16 + pass] = bi_; bufd[qi][bs] = 1e30f; }
    __syncthreads();
  }
}

// ---------------------------------------------------------------------------
// Tiled GEMM (r29-validated). 64 rows/block, 256 thr, 8 rows x 4 ch each.
// ---------------------------------------------------------------------------
template<int KD>
__global__ __launch_bounds__(256) void gemm_k(const float* __restrict__ A,
                                              const float* __restrict__ Wg,
                                              const float* __restrict__ bias,
                                              float* __restrict__ out){
  __shared__ __align__(16) float Wl[KD*128];
  __shared__ __align__(16) float At[KD*68];

  int t = threadIdx.x;
  int r0 = blockIdx.x * 64;

  for (int i = t; i < KD*32; i += 256)
    reinterpret_cast<float4*>(Wl)[i] = reinterpret_cast<const float4*>(Wg)[i];
  {
    int kk = t & (KD-1); int rr = t / KD;
    for (int r = rr; r < 64; r += 256/KD)
      At[kk*68 + r] = A[(r0+r)*KD + kk];
  }
  __syncthreads();

  int lc = t & 31, ch = lc*4, rg = t >> 5;
  float bb[4] = {0.f, 0.f, 0.f, 0.f};
  if (bias){ float4 b4 = ld4(bias + ch); bb[0]=b4.x; bb[1]=b4.y; bb[2]=b4.z; bb[3]=b4.w; }
  float acc[8][4];
  #pragma unroll
  for (int j = 0; j < 8; j++){ acc[j][0]=bb[0]; acc[j][1]=bb[1]; acc[j][2]=bb[2]; acc[j][3]=bb[3]; }

  #pragma unroll 4
  for (int kk = 0; kk < KD; kk++){
    float4 w = ld4(&Wl[kk*128 + ch]);
    float4 a = ld4(&At[kk*68 + rg*8]);
    float4 b = ld4(&At[kk*68 + rg*8 + 4]);
    float wa[4] = {w.x, w.y, w.z, w.w};
    float ta[8] = {a.x, a.y, a.z, a.w, b.x, b.y, b.z, b.w};
    #pragma unroll
    for (int j = 0; j < 8; j++)
      #pragma unroll
      for (int c = 0; c < 4; c++)
        acc[j][c] = fmaf(ta[j], wa[c], acc[j][c]);
  }

  #pragma unroll
  for (int j = 0; j < 8; j++){
    int row = r0 + rg*8 + j;
    st4(&out[row*128 + ch], make_float4(acc[j][0], acc[j][1], acc[j][2], acc[j][3]));
  }
}

// ---------------------------------------------------------------------------
// Fused per-point core (r29-validated). 4 points/block, 256 thr.
// ---------------------------------------------------------------------------
__device__ __forceinline__ void mm_step(const float* Wl, const float* bufp,
                                        int jo, int ch, float acc[8][4]){
  #pragma unroll 4
  for (int kk = 0; kk < 128; kk++){
    float4 w = ld4(&Wl[kk*128 + ch]);
    float4 a = ld4(&bufp[kk*16 + jo]);
    float4 b = ld4(&bufp[kk*16 + jo + 4]);
    float wa[4] = {w.x, w.y, w.z, w.w};
    float ta[8] = {a.x, a.y, a.z, a.w, b.x, b.y, b.z, b.w};
    #pragma unroll
    for (int j = 0; j < 8; j++)
      #pragma unroll
      for (int c = 0; c < 4; c++)
        acc[j][c] = fmaf(ta[j], wa[c], acc[j][c]);
  }
}

__global__ __launch_bounds__(256) void pt_core(
    const float* __restrict__ xyz, const int* __restrict__ knn,
    const float* __restrict__ Qf, const float* __restrict__ Kf, const float* __restrict__ Vf,
    const float* __restrict__ d1w, const float* __restrict__ d1b,
    const float* __restrict__ d2w, const float* __restrict__ d2b,
    const float* __restrict__ g1w, const float* __restrict__ g1b,
    const float* __restrict__ g2w, const float* __restrict__ g2b,
    float* __restrict__ agg_out){
  __shared__ __align__(16) float Wl[128*128];
  __shared__ __align__(16) float buf[4][128*16];
  __shared__ __align__(16) float pbuf[4][128*16];
  __shared__ __align__(16) float rels[4][16*4];
  __shared__ int idxl[4][16];

  int tid = threadIdx.x;
  int wv = tid >> 6, lane = tid & 63, half = lane >> 5, lc = lane & 31;
  int ch = lc*4, jo = half*8;
  int n = blockIdx.x*4 + wv;

  for (int i = tid; i < 4096; i += 256)
    reinterpret_cast<float4*>(Wl)[i] = reinterpret_cast<const float4*>(d2w)[i];
  if (tid < 64){
    int p = tid >> 4, j = tid & 15;
    int row = blockIdx.x*4 + p;
    int gi = (row >> 12)*NPTS + knn[row*16 + j];
    idxl[p][j] = gi;
    rels[p][j*4+0] = xyz[row*3+0] - xyz[gi*3+0];
    rels[p][j*4+1] = xyz[row*3+1] - xyz[gi*3+1];
    rels[p][j*4+2] = xyz[row*3+2] - xyz[gi*3+2];
    rels[p][j*4+3] = 0.f;
  }
  float4 v0 = ld4(d1w + ch), v1 = ld4(d1w + 128 + ch), v2 = ld4(d1w + 256 + ch);
  float4 vb = ld4(d1b + ch);
  float dc[3][4] = {{v0.x,v0.y,v0.z,v0.w},{v1.x,v1.y,v1.z,v1.w},{v2.x,v2.y,v2.z,v2.w}};
  float db1[4] = {vb.x, vb.y, vb.z, vb.w};
  float4 b2 = ld4(d2b + ch); float db2[4] = {b2.x, b2.y, b2.z, b2.w};
  __syncthreads();

  float* bufp  = buf[wv];
  float* pbufp = pbuf[wv];

  {
    float tv[4][8];
    #pragma unroll
    for (int jj = 0; jj < 8; jj++){
      float4 r = ld4(&rels[wv][(jo+jj)*4]);
      float rr[3] = {r.x, r.y, r.z};
      #pragma unroll
      for (int c = 0; c < 4; c++){
        float v = db1[c];
        #pragma unroll
        for (int cc = 0; cc < 3; cc++) v = fmaf(rr[cc], dc[cc][c], v);
        tv[c][jj] = fmaxf(v, 0.f);
      }
    }
    #pragma unroll
    for (int c = 0; c < 4; c++){
      st4(&bufp[(ch+c)*16 + jo],     make_float4(tv[c][0], tv[c][1], tv[c][2], tv[c][3]));
      st4(&bufp[(ch+c)*16 + jo + 4], make_float4(tv[c][4], tv[c][5], tv[c][6], tv[c][7]));
    }
  }
  __syncthreads();

  float acc[8][4];
  #pragma unroll
  for (int j = 0; j < 8; j++){ acc[j][0]=db2[0]; acc[j][1]=db2[1]; acc[j][2]=db2[2]; acc[j][3]=db2[3]; }
  mm_step(Wl, bufp, jo, ch, acc);

  #pragma unroll
  for (int c = 0; c < 4; c++){
    st4(&pbufp[(ch+c)*16 + jo],     make_float4(acc[0][c], acc[1][c], acc[2][c], acc[3][c]));
    st4(&pbufp[(ch+c)*16 + jo + 4], make_float4(acc[4][c], acc[5][c], acc[6][c], acc[7][c]));
  }

  {
    float4 q4 = ld4(&Qf[(long)n*128 + ch]);
    float qa[4] = {q4.x, q4.y, q4.z, q4.w};
    float hv[8][4];
    #pragma unroll
    for (int jj = 0; jj < 8; jj++){
      int gi = idxl[wv][jo+jj];
      float4 k4 = ld4(&Kf[(long)gi*128 + ch]);
      float ka[4] = {k4.x, k4.y, k4.z, k4.w};
      #pragma unroll
      for (int c = 0; c < 4; c++) hv[jj][c] = qa[c] - ka[c] + acc[jj][c];
    }
    #pragma unroll
    for (int c = 0; c < 4; c++){
      st4(&bufp[(ch+c)*16 + jo],     make_float4(hv[0][c], hv[1][c], hv[2][c], hv[3][c]));
      st4(&bufp[(ch+c)*16 + jo + 4], make_float4(hv[4][c], hv[5][c], hv[6][c], hv[7][c]));
    }
  }
  __syncthreads();

  for (int i = tid; i < 4096; i += 256)
    reinterpret_cast<float4*>(Wl)[i] = reinterpret_cast<const float4*>(g1w)[i];
  __syncthreads();
  {
    float4 gb = ld4(g1b + ch); float g[4] = {gb.x, gb.y, gb.z, gb.w};
    #pragma unroll
    for (int j = 0; j < 8; j++){ acc[j][0]=g[0]; acc[j][1]=g[1]; acc[j][2]=g[2]; acc[j][3]=g[3]; }
  }
  mm_step(Wl, bufp, jo, ch, acc);
  #pragma unroll
  for (int j = 0; j < 8; j++)
    #pragma unroll
    for (int c = 0; c < 4; c++) acc[j][c] = fmaxf(acc[j][c], 0.f);
  __syncthreads();
  #pragma unroll
  for (int c = 0; c < 4; c++){
    st4(&bufp[(ch+c)*16 + jo],     make_float4(acc[0][c], acc[1][c], acc[2][c], acc[3][c]));
    st4(&bufp[(ch+c)*16 + jo + 4], make_float4(acc[4][c], acc[5][c], acc[6][c], acc[7][c]));
  }
  __syncthreads();

  for (int i = tid; i < 4096; i += 256)
    reinterpret_cast<float4*>(Wl)[i] = reinterpret_cast<const float4*>(g2w)[i];
  __syncthreads();
  {
    float4 gb = ld4(g2b + ch); float g[4] = {gb.x, gb.y, gb.z, gb.w};
    #pragma unroll
    for (int j = 0; j < 8; j++){ acc[j][0]=g[0]; acc[j][1]=g[1]; acc[j][2]=g[2]; acc[j][3]=g[3]; }
  }
  mm_step(Wl, bufp, jo, ch, acc);

  const float sc = 0.08838834764831845f;
  #pragma unroll
  for (int j = 0; j < 8; j++)
    #pragma unroll
    for (int c = 0; c < 4; c++) acc[j][c] *= sc;
  float mx[4], inv[4];
  #pragma unroll
  for (int c = 0; c < 4; c++){
    float m = acc[0][c];
    #pragma unroll
    for (int j = 1; j < 8; j++) m = fmaxf(m, acc[j][c]);
    m = fmaxf(m, __shfl_xor(m, 32));
    mx[c] = m;
  }
  #pragma unroll
  for (int j = 0; j < 8; j++)
    #pragma unroll
    for (int c = 0; c < 4; c++) acc[j][c] = __expf(acc[j][c] - mx[c]);
  #pragma unroll
  for (int c = 0; c < 4; c++){
    float s = 0.f;
    #pragma unroll
    for (int j = 0; j < 8; j++) s += acc[j][c];
    s += __shfl_xor(s, 32);
    inv[c] = 1.0f / s;
  }
  #pragma unroll
  for (int j = 0; j < 8; j++)
    #pragma unroll
    for (int c = 0; c < 4; c++) acc[j][c] *= inv[c];

  float pv[4][8];
  #pragma unroll
  for (int c = 0; c < 4; c++){
    float4 pa = ld4(&pbufp[(ch+c)*16 + jo]);
    float4 pb = ld4(&pbufp[(ch+c)*16 + jo + 4]);
    pv[c][0]=pa.x; pv[c][1]=pa.y; pv[c][2]=pa.z; pv[c][3]=pa.w;
    pv[c][4]=pb.x; pv[c][5]=pb.y; pv[c][6]=pb.z; pv[c][7]=pb.w;
  }
  float ag[4] = {0.f, 0.f, 0.f, 0.f};
  #pragma unroll
  for (int jj = 0; jj < 8; jj++){
    int gi = idxl[wv][jo+jj];
    float4 v4 = ld4(&Vf[(long)gi*128 + ch]);
    float va[4] = {v4.x, v4.y, v4.z, v4.w};
    #pragma unroll
    for (int c = 0; c < 4; c++) ag[c] = fmaf(acc[jj][c], va[c] + pv[c][jj], ag[c]);
  }
  #pragma unroll
  for (int c = 0; c < 4; c++) ag[c] += __shfl_xor(ag[c], 32);
  if (half == 0)
    st4(&agg_out[(long)n*128 + ch], make_float4(ag[0], ag[1], ag[2], ag[3]));
}

// ---------------------------------------------------------------------------
extern "C" void kernel_launch(void* const* d_in, const int* in_sizes, int n_in,
                              void* d_out, int out_size, void* d_ws, size_t ws_size,
                              hipStream_t stream) {
  const float* xyz      = (const float*)d_in[0];
  const float* features = (const float*)d_in[1];
  const float* fc1_w    = (const float*)d_in[2];
  const float* fc1_b    = (const float*)d_in[3];
  const float* fc2_w    = (const float*)d_in[4];
  const float* fc2_b    = (const float*)d_in[5];
  const float* d1_w     = (const float*)d_in[6];
  const float* d1_b     = (const float*)d_in[7];
  const float* d2_w     = (const float*)d_in[8];
  const float* d2_b     = (const float*)d_in[9];
  const float* g1_w     = (const float*)d_in[10];
  const float* g1_b     = (const float*)d_in[11];
  const float* g2_w     = (const float*)d_in[12];
  const float* g2_b     = (const float*)d_in[13];
  const float* wq_w     = (const float*)d_in[14];
  const float* wk_w     = (const float*)d_in[15];
  const float* wv_w     = (const float*)d_in[16];
  float* out = (float*)d_out;

  char* ws = (char*)d_ws;
  const size_t SZ = (size_t)TROWS * 128 * sizeof(float);  // 16.78 MB
  float*  X    = (float*)(ws);
  float*  Qf   = (float*)(ws + SZ);
  float*  Kf   = (float*)(ws + 2*SZ);
  float*  Vf   = (float*)(ws + 3*SZ);
  int*    kn   = (int*)  (ws + 4*SZ);
  float4* pts4 = (float4*)(ws + 4*SZ + (size_t)TROWS*16*sizeof(int));

  knn_prep   <<<dim3((TROWS+255)/256), dim3(256), 0, stream>>>(xyz, pts4);
  knn_collect<<<dim3(TROWS/NQ), dim3(256), 0, stream>>>(pts4, kn);
  gemm_k<64> <<<dim3(TROWS/64), dim3(256), 0, stream>>>(features, fc1_w, fc1_b, X);
  gemm_k<128><<<dim3(TROWS/64), dim3(256), 0, stream>>>(X, wq_w, nullptr, Qf);
  gemm_k<128><<<dim3(TROWS/64), dim3(256), 0, stream>>>(X, wk_w, nullptr, Kf);
  gemm_k<128><<<dim3(TROWS/64), dim3(256), 0, stream>>>(X, wv_w, nullptr, Vf);
  pt_core<<<dim3(TROWS/4), dim3(256), 0, stream>>>(xyz, kn, Qf, Kf, Vf,
                                                   d1_w, d1_b, d2_w, d2_b,
                                                   g1_w, g1_b, g2_w, g2_b, out);
  gemm_k<128><<<dim3(TROWS/64), dim3(256), 0, stream>>>(out, fc2_w, fc2_b, out);
}

// Round 31
// 978.011 us; speedup vs baseline: 5.5363x; 1.4575x over previous
//
#include <hip/hip_runtime.h>

// PointTransformerLayer. kNN bits FROZEN (r28). r31: pt_core rebuild —
// j-major [16][132] tile (conflict-free stores/reads), P in registers,
// 32KB chunked weight staging -> 2 blocks/CU. FMA order unchanged vs r30
// (bitwise-identical output).

#define NPTS 4096
#define BATCH 8
#define TROWS (BATCH * NPTS)   // 32768
#define CAP 512
#define NQ 8
#define NPART 32

__device__ __forceinline__ float4 ld4(const float* p){ return *reinterpret_cast<const float4*>(p); }
__device__ __forceinline__ void st4(float* p, float4 v){ *reinterpret_cast<float4*>(p) = v; }
__device__ __forceinline__ float opaque(float x){ asm volatile("" : "+v"(x)); return x; }

// ---------------------------------------------------------------------------
__global__ __launch_bounds__(256) void knn_prep(const float* __restrict__ xyz,
                                                float4* __restrict__ pts4){
  int i = blockIdx.x*256 + threadIdx.x;
  if (i >= TROWS) return;
  float x = xyz[3*i], y = xyz[3*i+1], z = xyz[3*i+2];
  float q0 = opaque(x*x), q1 = opaque(y*y), q2 = opaque(z*z);
  float s02 = opaque(q0 + q2);
  float s   = opaque(s02 + q1);
  pts4[i] = make_float4(x, y, z, s);
}

__global__ __launch_bounds__(256) void knn_collect(const float4* __restrict__ pts4,
                                                   int* __restrict__ knn){
  __shared__ float bufd[NQ][CAP];
  __shared__ int   bufi[NQ][CAP];
  __shared__ int   cnt[NQ];
  __shared__ int   anyflag;

  int tid = threadIdx.x;
  int qi = tid >> 5, part = tid & 31;
  int b  = blockIdx.x / (NPTS/NQ);
  int q0 = (blockIdx.x % (NPTS/NQ)) * NQ;
  int row = b*NPTS + q0 + qi;
  const float4* base = pts4 + b*NPTS;
  float4 Pq = pts4[row];

  float T = 0.03f;
  for (int round = 0; round < 14; ++round){
    if (tid == 0) anyflag = 0;
    __syncthreads();
    bool active = (round == 0) || (cnt[qi] < 16);
    __syncthreads();
    if (active && part == 0){ cnt[qi] = 0; anyflag = 1; }
    __syncthreads();
    if (!anyflag) break;
    if (active){
      for (int i = part; i < NPTS; i += NPART){
        float4 P = base[i];
        float p0 = opaque(Pq.x*P.x);
        float f1 = opaque(fmaf(Pq.y, P.y, p0));
        float d  = opaque(fmaf(Pq.z, P.z, f1));
        float ssum = opaque(Pq.w + P.w);
        float dist = opaque(ssum - 2.0f*d);
        if (dist < T){
          int p = atomicAdd(&cnt[qi], 1);
          if (p < CAP){ bufd[qi][p] = dist; bufi[qi][p] = i; }
        }
      }
    }
    T *= 1.5f;
    __syncthreads();
  }

  int n_c = cnt[qi]; if (n_c > CAP) n_c = CAP;
  for (int pass = 0; pass < 16; ++pass){
    float bd = 1e30f; int bi_ = 0x7fffffff; int bs = 0;
    for (int e = part; e < n_c; e += NPART){
      float v = bufd[qi][e]; int ix = bufi[qi][e];
      if (v < bd || (v == bd && ix < bi_)){ bd = v; bi_ = ix; bs = e; }
    }
    #pragma unroll
    for (int off = 1; off < 32; off <<= 1){
      float od = __shfl_xor(bd, off); int oi = __shfl_xor(bi_, off); int os = __shfl_xor(bs, off);
      if (od < bd || (od == bd && oi < bi_)){ bd = od; bi_ = oi; bs = os; }
    }
    if (part == 0){ knn[row*16 + pass] = bi_; bufd[qi][bs] = 1e30f; }
    __syncthreads();
  }
}

// ---------------------------------------------------------------------------
template<int KD>
__global__ __launch_bounds__(256) void gemm_k(const float* __restrict__ A,
                                              const float* __restrict__ Wg,
                                              const float* __restrict__ bias,
                                              float* __restrict__ out){
  __shared__ __align__(16) float Wl[KD*128];
  __shared__ __align__(16) float At[KD*68];

  int t = threadIdx.x;
  int r0 = blockIdx.x * 64;

  for (int i = t; i < KD*32; i += 256)
    reinterpret_cast<float4*>(Wl)[i] = reinterpret_cast<const float4*>(Wg)[i];
  {
    int kk = t & (KD-1); int rr = t / KD;
    for (int r = rr; r < 64; r += 256/KD)
      At[kk*68 + r] = A[(r0+r)*KD + kk];
  }
  __syncthreads();

  int lc = t & 31, ch = lc*4, rg = t >> 5;
  float bb[4] = {0.f, 0.f, 0.f, 0.f};
  if (bias){ float4 b4 = ld4(bias + ch); bb[0]=b4.x; bb[1]=b4.y; bb[2]=b4.z; bb[3]=b4.w; }
  float acc[8][4];
  #pragma unroll
  for (int j = 0; j < 8; j++){ acc[j][0]=bb[0]; acc[j][1]=bb[1]; acc[j][2]=bb[2]; acc[j][3]=bb[3]; }

  #pragma unroll 4
  for (int kk = 0; kk < KD; kk++){
    float4 w = ld4(&Wl[kk*128 + ch]);
    float4 a = ld4(&At[kk*68 + rg*8]);
    float4 b = ld4(&At[kk*68 + rg*8 + 4]);
    float wa[4] = {w.x, w.y, w.z, w.w};
    float ta[8] = {a.x, a.y, a.z, a.w, b.x, b.y, b.z, b.w};
    #pragma unroll
    for (int j = 0; j < 8; j++)
      #pragma unroll
      for (int c = 0; c < 4; c++)
        acc[j][c] = fmaf(ta[j], wa[c], acc[j][c]);
  }

  #pragma unroll
  for (int j = 0; j < 8; j++){
    int row = r0 + rg*8 + j;
    st4(&out[row*128 + ch], make_float4(acc[j][0], acc[j][1], acc[j][2], acc[j][3]));
  }
}

// ---------------------------------------------------------------------------
// pt_core: 4 points/block (1/wave), 256 thr. Work tile j-major [16][132]
// (conflict-free). Weights staged in 32KB (64-row) chunks. P in registers.
// FMA accumulation order identical to the validated r30 kernel.
// ---------------------------------------------------------------------------
#define TSTRIDE 132

__device__ __forceinline__ void mm_half(const float* __restrict__ Wl,
                                        const float* __restrict__ bufp,
                                        int kbase, int jo, int ch,
                                        float acc[8][4]){
  #pragma unroll 2
  for (int g = 0; g < 16; g++){
    int k0 = g*4;
    float4 w0 = ld4(&Wl[(k0+0)*128 + ch]);
    float4 w1 = ld4(&Wl[(k0+1)*128 + ch]);
    float4 w2 = ld4(&Wl[(k0+2)*128 + ch]);
    float4 w3 = ld4(&Wl[(k0+3)*128 + ch]);
    float wa[4][4] = {{w0.x,w0.y,w0.z,w0.w},{w1.x,w1.y,w1.z,w1.w},
                      {w2.x,w2.y,w2.z,w2.w},{w3.x,w3.y,w3.z,w3.w}};
    float4 aj[8];
    #pragma unroll
    for (int j = 0; j < 8; j++)
      aj[j] = ld4(&bufp[(jo+j)*TSTRIDE + kbase + k0]);
    #pragma unroll
    for (int j = 0; j < 8; j++){
      float a0=aj[j].x, a1=aj[j].y, a2=aj[j].z, a3=aj[j].w;
      #pragma unroll
      for (int c = 0; c < 4; c++){
        acc[j][c] = fmaf(a0, wa[0][c], acc[j][c]);
        acc[j][c] = fmaf(a1, wa[1][c], acc[j][c]);
        acc[j][c] = fmaf(a2, wa[2][c], acc[j][c]);
        acc[j][c] = fmaf(a3, wa[3][c], acc[j][c]);
      }
    }
  }
}

__global__ __launch_bounds__(256) void pt_core(
    const float* __restrict__ xyz, const int* __restrict__ knn,
    const float* __restrict__ Qf, const float* __restrict__ Kf, const float* __restrict__ Vf,
    const float* __restrict__ d1w, const float* __restrict__ d1b,
    const float* __restrict__ d2w, const float* __restrict__ d2b,
    const float* __restrict__ g1w, const float* __restrict__ g1b,
    const float* __restrict__ g2w, const float* __restrict__ g2b,
    float* __restrict__ agg_out){
  __shared__ __align__(16) float Wl[64*128];          // 32KB weight chunk
  __shared__ __align__(16) float buf[4][16*TSTRIDE];  // 33.8KB work tiles
  __shared__ __align__(16) float rels[4][16*4];
  __shared__ int idxl[4][16];

  int tid = threadIdx.x;
  int wv = tid >> 6, lane = tid & 63, half = lane >> 5, lc = lane & 31;
  int ch = lc*4, jo = half*8;
  int n = blockIdx.x*4 + wv;
  float* bufp = buf[wv];

  if (tid < 64){
    int p = tid >> 4, j = tid & 15;
    int row = blockIdx.x*4 + p;
    int gi = (row >> 12)*NPTS + knn[row*16 + j];
    idxl[p][j] = gi;
    rels[p][j*4+0] = xyz[row*3+0] - xyz[gi*3+0];
    rels[p][j*4+1] = xyz[row*3+1] - xyz[gi*3+1];
    rels[p][j*4+2] = xyz[row*3+2] - xyz[gi*3+2];
    rels[p][j*4+3] = 0.f;
  }
  float4 v0 = ld4(d1w + ch), v1 = ld4(d1w + 128 + ch), v2 = ld4(d1w + 256 + ch);
  float4 vb = ld4(d1b + ch);
  float dc[3][4] = {{v0.x,v0.y,v0.z,v0.w},{v1.x,v1.y,v1.z,v1.w},{v2.x,v2.y,v2.z,v2.w}};
  float db1[4] = {vb.x, vb.y, vb.z, vb.w};
  float4 b2 = ld4(d2b + ch); float db2[4] = {b2.x, b2.y, b2.z, b2.w};
  __syncthreads();

  // T = relu(rel @ d1 + d1_b) -> buf (j-major, conflict-free)
  {
    #pragma unroll
    for (int jj = 0; jj < 8; jj++){
      float4 r = ld4(&rels[wv][(jo+jj)*4]);
      float rr[3] = {r.x, r.y, r.z};
      float tv[4];
      #pragma unroll
      for (int c = 0; c < 4; c++){
        float v = db1[c];
        #pragma unroll
        for (int cc = 0; cc < 3; cc++) v = fmaf(rr[cc], dc[cc][c], v);
        tv[c] = fmaxf(v, 0.f);
      }
      st4(&bufp[(jo+jj)*TSTRIDE + ch], make_float4(tv[0], tv[1], tv[2], tv[3]));
    }
  }

  // P = T @ d2 + d2_b  (chunked weights; P stays in registers)
  float pacc[8][4];
  #pragma unroll
  for (int j = 0; j < 8; j++){ pacc[j][0]=db2[0]; pacc[j][1]=db2[1]; pacc[j][2]=db2[2]; pacc[j][3]=db2[3]; }
  for (int i = tid; i < 2048; i += 256)
    reinterpret_cast<float4*>(Wl)[i] = reinterpret_cast<const float4*>(d2w)[i];
  __syncthreads();
  mm_half(Wl, bufp, 0, jo, ch, pacc);
  __syncthreads();
  for (int i = tid; i < 2048; i += 256)
    reinterpret_cast<float4*>(Wl)[i] = reinterpret_cast<const float4*>(d2w + 64*128)[i];
  __syncthreads();
  mm_half(Wl, bufp, 64, jo, ch, pacc);
  __syncthreads();

  // h = q - k + P -> buf
  {
    float4 q4 = ld4(&Qf[(long)n*128 + ch]);
    float qa[4] = {q4.x, q4.y, q4.z, q4.w};
    #pragma unroll
    for (int jj = 0; jj < 8; jj++){
      int gi = idxl[wv][jo+jj];
      float4 k4 = ld4(&Kf[(long)gi*128 + ch]);
      float hv[4] = {qa[0]-k4.x+pacc[jj][0], qa[1]-k4.y+pacc[jj][1],
                     qa[2]-k4.z+pacc[jj][2], qa[3]-k4.w+pacc[jj][3]};
      st4(&bufp[(jo+jj)*TSTRIDE + ch], make_float4(hv[0], hv[1], hv[2], hv[3]));
    }
  }

  // a1 = relu(h @ g1 + g1_b)
  float acc[8][4];
  {
    float4 gb = ld4(g1b + ch); float g[4] = {gb.x, gb.y, gb.z, gb.w};
    #pragma unroll
    for (int j = 0; j < 8; j++){ acc[j][0]=g[0]; acc[j][1]=g[1]; acc[j][2]=g[2]; acc[j][3]=g[3]; }
  }
  for (int i = tid; i < 2048; i += 256)
    reinterpret_cast<float4*>(Wl)[i] = reinterpret_cast<const float4*>(g1w)[i];
  __syncthreads();
  mm_half(Wl, bufp, 0, jo, ch, acc);
  __syncthreads();
  for (int i = tid; i < 2048; i += 256)
    reinterpret_cast<float4*>(Wl)[i] = reinterpret_cast<const float4*>(g1w + 64*128)[i];
  __syncthreads();
  mm_half(Wl, bufp, 64, jo, ch, acc);
  __syncthreads();   // all reads of h done before overwriting buf with a1

  #pragma unroll
  for (int jj = 0; jj < 8; jj++){
    float a0 = fmaxf(acc[jj][0], 0.f), a1v = fmaxf(acc[jj][1], 0.f);
    float a2 = fmaxf(acc[jj][2], 0.f), a3 = fmaxf(acc[jj][3], 0.f);
    st4(&bufp[(jo+jj)*TSTRIDE + ch], make_float4(a0, a1v, a2, a3));
  }

  // logits = a1 @ g2 + g2_b
  {
    float4 gb = ld4(g2b + ch); float g[4] = {gb.x, gb.y, gb.z, gb.w};
    #pragma unroll
    for (int j = 0; j < 8; j++){ acc[j][0]=g[0]; acc[j][1]=g[1]; acc[j][2]=g[2]; acc[j][3]=g[3]; }
  }
  for (int i = tid; i < 2048; i += 256)
    reinterpret_cast<float4*>(Wl)[i] = reinterpret_cast<const float4*>(g2w)[i];
  __syncthreads();
  mm_half(Wl, bufp, 0, jo, ch, acc);
  __syncthreads();
  for (int i = tid; i < 2048; i += 256)
    reinterpret_cast<float4*>(Wl)[i] = reinterpret_cast<const float4*>(g2w + 64*128)[i];
  __syncthreads();
  mm_half(Wl, bufp, 64, jo, ch, acc);

  // softmax over 16 neighbors per channel (halves via shfl_xor 32)
  const float sc = 0.08838834764831845f;
  #pragma unroll
  for (int j = 0; j < 8; j++)
    #pragma unroll
    for (int c = 0; c < 4; c++) acc[j][c] *= sc;
  float mx[4], inv[4];
  #pragma unroll
  for (int c = 0; c < 4; c++){
    float m = acc[0][c];
    #pragma unroll
    for (int j = 1; j < 8; j++) m = fmaxf(m, acc[j][c]);
    m = fmaxf(m, __shfl_xor(m, 32));
    mx[c] = m;
  }
  #pragma unroll
  for (int j = 0; j < 8; j++)
    #pragma unroll
    for (int c = 0; c < 4; c++) acc[j][c] = __expf(acc[j][c] - mx[c]);
  #pragma unroll
  for (int c = 0; c < 4; c++){
    float s = 0.f;
    #pragma unroll
    for (int j = 0; j < 8; j++) s += acc[j][c];
    s += __shfl_xor(s, 32);
    inv[c] = 1.0f / s;
  }
  #pragma unroll
  for (int j = 0; j < 8; j++)
    #pragma unroll
    for (int c = 0; c < 4; c++) acc[j][c] *= inv[c];

  // agg = sum_j attn * (V + P)   (P from registers)
  float ag[4] = {0.f, 0.f, 0.f, 0.f};
  #pragma unroll
  for (int jj = 0; jj < 8; jj++){
    int gi = idxl[wv][jo+jj];
    float4 v4 = ld4(&Vf[(long)gi*128 + ch]);
    float va[4] = {v4.x, v4.y, v4.z, v4.w};
    #pragma unroll
    for (int c = 0; c < 4; c++) ag[c] = fmaf(acc[jj][c], va[c] + pacc[jj][c], ag[c]);
  }
  #pragma unroll
  for (int c = 0; c < 4; c++) ag[c] += __shfl_xor(ag[c], 32);
  if (half == 0)
    st4(&agg_out[(long)n*128 + ch], make_float4(ag[0], ag[1], ag[2], ag[3]));
}

// ---------------------------------------------------------------------------
extern "C" void kernel_launch(void* const* d_in, const int* in_sizes, int n_in,
                              void* d_out, int out_size, void* d_ws, size_t ws_size,
                              hipStream_t stream) {
  const float* xyz      = (const float*)d_in[0];
  const float* features = (const float*)d_in[1];
  const float* fc1_w    = (const float*)d_in[2];
  const float* fc1_b    = (const float*)d_in[3];
  const float* fc2_w    = (const float*)d_in[4];
  const float* fc2_b    = (const float*)d_in[5];
  const float* d1_w     = (const float*)d_in[6];
  const float* d1_b     = (const float*)d_in[7];
  const float* d2_w     = (const float*)d_in[8];
  const float* d2_b     = (const float*)d_in[9];
  const float* g1_w     = (const float*)d_in[10];
  const float* g1_b     = (const float*)d_in[11];
  const float* g2_w     = (const float*)d_in[12];
  const float* g2_b     = (const float*)d_in[13];
  const float* wq_w     = (const float*)d_in[14];
  const float* wk_w     = (const float*)d_in[15];
  const float* wv_w     = (const float*)d_in[16];
  float* out = (float*)d_out;

  char* ws = (char*)d_ws;
  const size_t SZ = (size_t)TROWS * 128 * sizeof(float);
  float*  X    = (float*)(ws);
  float*  Qf   = (float*)(ws + SZ);
  float*  Kf   = (float*)(ws + 2*SZ);
  float*  Vf   = (float*)(ws + 3*SZ);
  int*    kn   = (int*)  (ws + 4*SZ);
  float4* pts4 = (float4*)(ws + 4*SZ + (size_t)TROWS*16*sizeof(int));

  knn_prep   <<<dim3((TROWS+255)/256), dim3(256), 0, stream>>>(xyz, pts4);
  knn_collect<<<dim3(TROWS/NQ), dim3(256), 0, stream>>>(pts4, kn);
  gemm_k<64> <<<dim3(TROWS/64), dim3(256), 0, stream>>>(features, fc1_w, fc1_b, X);
  gemm_k<128><<<dim3(TROWS/64), dim3(256), 0, stream>>>(X, wq_w, nullptr, Qf);
  gemm_k<128><<<dim3(TROWS/64), dim3(256), 0, stream>>>(X, wk_w, nullptr, Kf);
  gemm_k<128><<<dim3(TROWS/64), dim3(256), 0, stream>>>(X, wv_w, nullptr, Vf);
  pt_core<<<dim3(TROWS/4), dim3(256), 0, stream>>>(xyz, kn, Qf, Kf, Vf,
                                                   d1_w, d1_b, d2_w, d2_b,
                                                   g1_w, g1_b, g2_w, g2_b, out);
  gemm_k<128><<<dim3(TROWS/64), dim3(256), 0, stream>>>(out, fc2_w, fc2_b, out);
}